// Round 5
// baseline (1047.933 us; speedup 1.0000x reference)
//
#include <hip/hip_runtime.h>
#include <hip/hip_bf16.h>

typedef __hip_bfloat16 bf16;

#define B_ 8
#define S_ 1024
#define D_ 512
#define H_ 8
#define HD_ 64
#define L_ 128
#define LH_ 16

__device__ __forceinline__ float bfu2f(unsigned short u) {
  unsigned int x = ((unsigned int)u) << 16;
  float f;
  __builtin_memcpy(&f, &x, 4);
  return f;
}

// ---------------- generic tiled f32 GEMM ----------------
// C(MxN) = A(MxK) @ B (+bias). BT: B is row-major (N,K) -> use B[n*ldb+k].
// ABF16: A elements are bf16. CBF16: store bf16. Requires M%64==0, N%64==0, K%16==0.
template<bool BT, bool BIAS, bool ABF16, bool CBF16>
__global__ __launch_bounds__(256) void gemm(const void* __restrict__ Ap, int lda,
                                            const void* __restrict__ Bp, int ldb,
                                            void* __restrict__ Cp, int ldc,
                                            const float* __restrict__ bias, int K) {
  __shared__ float As[16][65];   // [k][m]
  __shared__ float Bs[16][65];   // [k][n]
  const int tid = threadIdx.x;
  const int m0 = blockIdx.y * 64, n0 = blockIdx.x * 64;
  const int ty = tid >> 4, tx = tid & 15;
  float acc[4][4] = {};
  for (int kt = 0; kt < K; kt += 16) {
    // stage A: 64 rows x 16 k
    {
      const int m = tid >> 2, kq = (tid & 3) * 4;
      if (ABF16) {
        const bf16* A = (const bf16*)Ap;
        ushort4 u = *reinterpret_cast<const ushort4*>(
            reinterpret_cast<const unsigned short*>(A) + (size_t)(m0 + m) * lda + kt + kq);
        As[kq + 0][m] = bfu2f(u.x);
        As[kq + 1][m] = bfu2f(u.y);
        As[kq + 2][m] = bfu2f(u.z);
        As[kq + 3][m] = bfu2f(u.w);
      } else {
        const float* A = (const float*)Ap;
        float4 v = *reinterpret_cast<const float4*>(A + (size_t)(m0 + m) * lda + kt + kq);
        As[kq + 0][m] = v.x;
        As[kq + 1][m] = v.y;
        As[kq + 2][m] = v.z;
        As[kq + 3][m] = v.w;
      }
    }
    // stage B: 16 k x 64 n
    if (BT) {
      const int n = tid >> 2, kq = (tid & 3) * 4;
      const float* Bf = (const float*)Bp;
      float4 v = *reinterpret_cast<const float4*>(Bf + (size_t)(n0 + n) * ldb + kt + kq);
      Bs[kq + 0][n] = v.x;
      Bs[kq + 1][n] = v.y;
      Bs[kq + 2][n] = v.z;
      Bs[kq + 3][n] = v.w;
    } else {
      const int k = tid >> 4, nq = (tid & 15) * 4;
      const float* Bf = (const float*)Bp;
      float4 v = *reinterpret_cast<const float4*>(Bf + (size_t)(kt + k) * ldb + n0 + nq);
      Bs[k][nq + 0] = v.x;
      Bs[k][nq + 1] = v.y;
      Bs[k][nq + 2] = v.z;
      Bs[k][nq + 3] = v.w;
    }
    __syncthreads();
#pragma unroll
    for (int k = 0; k < 16; ++k) {
      float a0 = As[k][ty * 4 + 0], a1 = As[k][ty * 4 + 1];
      float a2 = As[k][ty * 4 + 2], a3 = As[k][ty * 4 + 3];
      float b0 = Bs[k][tx * 4 + 0], b1 = Bs[k][tx * 4 + 1];
      float b2 = Bs[k][tx * 4 + 2], b3 = Bs[k][tx * 4 + 3];
      acc[0][0] += a0 * b0; acc[0][1] += a0 * b1; acc[0][2] += a0 * b2; acc[0][3] += a0 * b3;
      acc[1][0] += a1 * b0; acc[1][1] += a1 * b1; acc[1][2] += a1 * b2; acc[1][3] += a1 * b3;
      acc[2][0] += a2 * b0; acc[2][1] += a2 * b1; acc[2][2] += a2 * b2; acc[2][3] += a2 * b3;
      acc[3][0] += a3 * b0; acc[3][1] += a3 * b1; acc[3][2] += a3 * b2; acc[3][3] += a3 * b3;
    }
    __syncthreads();
  }
#pragma unroll
  for (int i = 0; i < 4; ++i)
#pragma unroll
    for (int j = 0; j < 4; ++j) {
      const size_t row = m0 + ty * 4 + i;
      const int col = n0 + tx * 4 + j;
      float v = acc[i][j];
      if (BIAS) v += bias[col];
      if (CBF16)
        reinterpret_cast<bf16*>(Cp)[row * ldc + col] = __float2bfloat16(v);
      else
        reinterpret_cast<float*>(Cp)[row * ldc + col] = v;
    }
}

// ---------------- bias_comb[j] = sum_d bq[d]*Wuk[j][d] ----------------
__global__ __launch_bounds__(64) void k_biascomb(const float* __restrict__ bq,
                                                 const float* __restrict__ Wuk,
                                                 float* __restrict__ bias_c) {
  int j = blockIdx.x, lane = threadIdx.x;
  float s = 0.f;
  for (int d = lane; d < D_; d += 64) s += bq[d] * Wuk[j * D_ + d];
#pragma unroll
  for (int off = 32; off > 0; off >>= 1) s += __shfl_down(s, off);
  if (lane == 0) bias_c[j] = s;
}

// ---------------- qk + masked softmax, one block per (bh, q-row) ----------
__global__ __launch_bounds__(256) void k_qk(const float* __restrict__ q_lat,
                                            const float* __restrict__ k_lat,
                                            const float* __restrict__ maskg,
                                            float* __restrict__ qk_out,
                                            float* __restrict__ aw_out) {
  const int q = blockIdx.x, bh = blockIdx.y, b = bh >> 3, h = bh & 7;
  const int tid = threadIdx.x;
  __shared__ float qs[16];
  __shared__ float red[8];
  if (tid < 16) qs[tid] = q_lat[(size_t)(b * S_ + q) * L_ + h * LH_ + tid];
  __syncthreads();
  const float mq = maskg[b * S_ + q];
  const size_t orow = (size_t)bh * S_ * S_ + (size_t)q * S_;

  float logit[4];
  float lmax = -INFINITY;
#pragma unroll
  for (int i = 0; i < 4; ++i) {
    const int k = tid + i * 256;
    const float* kr = k_lat + (size_t)(b * S_ + k) * L_ + h * LH_;
    float d = 0.f;
#pragma unroll
    for (int t = 0; t < 16; ++t) d += qs[t] * kr[t];
    d *= 0.25f;                       // / sqrt(16)
    qk_out[orow + k] = d;
    const float m = fminf(1.f, __fadd_rn(mq, maskg[b * S_ + k]));
    logit[i] = __fadd_rn(d, __fmul_rn(m, -1e9f));   // no fma: match ref rounding
    lmax = fmaxf(lmax, logit[i]);
  }
  // block max
  for (int off = 32; off > 0; off >>= 1) lmax = fmaxf(lmax, __shfl_down(lmax, off));
  if ((tid & 63) == 0) red[tid >> 6] = lmax;
  __syncthreads();
  if (tid == 0) red[4] = fmaxf(fmaxf(red[0], red[1]), fmaxf(red[2], red[3]));
  __syncthreads();
  const float M = red[4];
  float e[4], ps = 0.f;
#pragma unroll
  for (int i = 0; i < 4; ++i) { e[i] = expf(logit[i] - M); ps += e[i]; }
  for (int off = 32; off > 0; off >>= 1) ps += __shfl_down(ps, off);
  if ((tid & 63) == 0) red[tid >> 6] = ps;
  __syncthreads();
  if (tid == 0) red[5] = (red[0] + red[1]) + (red[2] + red[3]);
  __syncthreads();
  const float inv = 1.f / red[5];
#pragma unroll
  for (int i = 0; i < 4; ++i) aw_out[orow + tid + i * 256] = e[i] * inv;
}

// ---------------- PV: attn[b,q,h*64+d] = sum_k aw[bh,q,k]*v[b,k,h*64+d] ----
__global__ __launch_bounds__(256) void k_pv(const float* __restrict__ aw,
                                            const bf16* __restrict__ v,
                                            bf16* __restrict__ attn) {
  __shared__ float As[16][65];   // [k][m]
  __shared__ float Bs[16][65];   // [k][n]
  const int bh = blockIdx.y, b = bh >> 3, h = bh & 7;
  const int m0 = blockIdx.x * 64;
  const int tid = threadIdx.x, ty = tid >> 4, tx = tid & 15;
  const float* A = aw + (size_t)bh * S_ * S_;
  float acc[4][4] = {};
  for (int kt = 0; kt < S_; kt += 16) {
    {
      const int m = tid >> 2, kq = (tid & 3) * 4;
      float4 w = *reinterpret_cast<const float4*>(A + (size_t)(m0 + m) * S_ + kt + kq);
      As[kq + 0][m] = w.x; As[kq + 1][m] = w.y; As[kq + 2][m] = w.z; As[kq + 3][m] = w.w;
    }
    {
      const int k = tid >> 4, nq = (tid & 15) * 4;
      ushort4 u = *reinterpret_cast<const ushort4*>(
          reinterpret_cast<const unsigned short*>(v) + (size_t)(b * S_ + kt + k) * D_ + h * HD_ + nq);
      Bs[k][nq + 0] = bfu2f(u.x); Bs[k][nq + 1] = bfu2f(u.y);
      Bs[k][nq + 2] = bfu2f(u.z); Bs[k][nq + 3] = bfu2f(u.w);
    }
    __syncthreads();
#pragma unroll
    for (int k = 0; k < 16; ++k) {
      float a0 = As[k][ty * 4 + 0], a1 = As[k][ty * 4 + 1];
      float a2 = As[k][ty * 4 + 2], a3 = As[k][ty * 4 + 3];
      float b0 = Bs[k][tx * 4 + 0], b1 = Bs[k][tx * 4 + 1];
      float b2 = Bs[k][tx * 4 + 2], b3 = Bs[k][tx * 4 + 3];
      acc[0][0] += a0 * b0; acc[0][1] += a0 * b1; acc[0][2] += a0 * b2; acc[0][3] += a0 * b3;
      acc[1][0] += a1 * b0; acc[1][1] += a1 * b1; acc[1][2] += a1 * b2; acc[1][3] += a1 * b3;
      acc[2][0] += a2 * b0; acc[2][1] += a2 * b1; acc[2][2] += a2 * b2; acc[2][3] += a2 * b3;
      acc[3][0] += a3 * b0; acc[3][1] += a3 * b1; acc[3][2] += a3 * b2; acc[3][3] += a3 * b3;
    }
    __syncthreads();
  }
#pragma unroll
  for (int i = 0; i < 4; ++i)
#pragma unroll
    for (int j = 0; j < 4; ++j)
      attn[(size_t)(b * S_ + m0 + ty * 4 + i) * D_ + h * HD_ + tx * 4 + j] =
          __float2bfloat16(acc[i][j]);
}

extern "C" void kernel_launch(void* const* d_in, const int* in_sizes, int n_in,
                              void* d_out, int out_size, void* d_ws, size_t ws_size,
                              hipStream_t stream) {
  const float* x    = (const float*)d_in[0];
  const float* mask = (const float*)d_in[1];
  const float* Wq   = (const float*)d_in[2];
  const float* bq   = (const float*)d_in[3];
  const float* Wckv = (const float*)d_in[4];
  const float* Wuk  = (const float*)d_in[5];
  const float* Wuv  = (const float*)d_in[6];
  const float* Wo   = (const float*)d_in[7];
  const float* bo   = (const float*)d_in[8];

  // outputs: f32, concatenated (out, attn_weights, qk_values)
  float* out    = (float*)d_out;                          // (B,S,D)
  float* aw_out = out + (size_t)B_ * S_ * D_;             // (B,H,S,S)
  float* qk_out = aw_out + (size_t)B_ * H_ * S_ * S_;     // (B,H,S,S)

  // workspace (~17 MB): Wcomb | bias_c | q_lat | k_lat | v_bf
  // attn_bf aliases [q_lat,k_lat] (dead after k_qk; sizes match exactly).
  uint8_t* p = (uint8_t*)d_ws;
  auto alloc = [&](size_t bytes) {
    void* r = p;
    p += (bytes + 255) & ~(size_t)255;
    return r;
  };
  float* Wcomb   = (float*)alloc((size_t)512 * 128 * 4);     // 256 KB
  float* bias_c  = (float*)alloc(128 * 4);
  float* q_lat   = (float*)alloc((size_t)8192 * 128 * 4);    // 4.19 MB
  float* k_lat   = (float*)alloc((size_t)8192 * 128 * 4);    // 4.19 MB
  bf16*  v_bf    = (bf16*)alloc((size_t)8192 * 512 * 2);     // 8.39 MB
  bf16*  attn_bf = (bf16*)q_lat;                             // alias, 8.39 MB

  // Wcomb(512x128) = Wq(512x512) @ Wuk^T   [B given as (N=128,K=512) row-major]
  gemm<true, false, false, false><<<dim3(2, 8), 256, 0, stream>>>(
      Wq, 512, Wuk, 512, Wcomb, 128, nullptr, 512);
  // bias_c = bq @ Wuk^T
  k_biascomb<<<128, 64, 0, stream>>>(bq, Wuk, bias_c);
  // q_lat(8192x128) = x @ Wcomb + bias_c
  gemm<false, true, false, false><<<dim3(2, 128), 256, 0, stream>>>(
      x, 512, Wcomb, 128, q_lat, 128, bias_c, 512);
  // k_lat(8192x128) = x @ Wckv
  gemm<false, false, false, false><<<dim3(2, 128), 256, 0, stream>>>(
      x, 512, Wckv, 128, k_lat, 128, nullptr, 512);
  // v(8192x512) = k_lat @ Wuv   (bf16 store)
  gemm<false, false, false, true><<<dim3(8, 128), 256, 0, stream>>>(
      k_lat, 128, Wuv, 512, v_bf, 512, nullptr, 128);
  // qk_values + attn_weights (f32, exact mask arithmetic)
  k_qk<<<dim3(1024, 64), 256, 0, stream>>>(q_lat, k_lat, mask, qk_out, aw_out);
  // attn = aw @ v   (bf16 store; overwrites q_lat/k_lat region — both dead)
  k_pv<<<dim3(16, 64), 256, 0, stream>>>(aw_out, v_bf, attn_bf);
  // out = attn @ Wo + bo
  gemm<false, true, true, false><<<dim3(8, 128), 256, 0, stream>>>(
      attn_bf, 512, Wo, 512, out, 512, bo, 512);
  (void)in_sizes; (void)n_in; (void)out_size; (void)ws_size;
}

// Round 6
// 736.423 us; speedup vs baseline: 1.4230x; 1.4230x over previous
//
#include <hip/hip_runtime.h>
#include <hip/hip_bf16.h>

typedef __hip_bfloat16 bf16;

#define B_ 8
#define S_ 1024
#define D_ 512
#define H_ 8
#define HD_ 64
#define L_ 128
#define LH_ 16

__device__ __forceinline__ float bfu2f(unsigned short u) {
  unsigned int x = ((unsigned int)u) << 16;
  float f;
  __builtin_memcpy(&f, &x, 4);
  return f;
}

// ---------------- generic tiled f32 GEMM ----------------
// C(MxN) = A(MxK) @ B (+bias). BT: B is row-major (N,K) -> use B[n*ldb+k].
// ABF16: A elements are bf16. CBF16: store bf16. Requires M%64==0, N%64==0, K%16==0.
template<bool BT, bool BIAS, bool ABF16, bool CBF16>
__global__ __launch_bounds__(256) void gemm(const void* __restrict__ Ap, int lda,
                                            const void* __restrict__ Bp, int ldb,
                                            void* __restrict__ Cp, int ldc,
                                            const float* __restrict__ bias, int K) {
  __shared__ float As[16][65];   // [k][m]
  __shared__ float Bs[16][65];   // [k][n]
  const int tid = threadIdx.x;
  const int m0 = blockIdx.y * 64, n0 = blockIdx.x * 64;
  const int ty = tid >> 4, tx = tid & 15;
  float acc[4][4] = {};
  for (int kt = 0; kt < K; kt += 16) {
    // stage A: 64 rows x 16 k
    {
      const int m = tid >> 2, kq = (tid & 3) * 4;
      if (ABF16) {
        const bf16* A = (const bf16*)Ap;
        ushort4 u = *reinterpret_cast<const ushort4*>(
            reinterpret_cast<const unsigned short*>(A) + (size_t)(m0 + m) * lda + kt + kq);
        As[kq + 0][m] = bfu2f(u.x);
        As[kq + 1][m] = bfu2f(u.y);
        As[kq + 2][m] = bfu2f(u.z);
        As[kq + 3][m] = bfu2f(u.w);
      } else {
        const float* A = (const float*)Ap;
        float4 v = *reinterpret_cast<const float4*>(A + (size_t)(m0 + m) * lda + kt + kq);
        As[kq + 0][m] = v.x;
        As[kq + 1][m] = v.y;
        As[kq + 2][m] = v.z;
        As[kq + 3][m] = v.w;
      }
    }
    // stage B: 16 k x 64 n
    if (BT) {
      const int n = tid >> 2, kq = (tid & 3) * 4;
      const float* Bf = (const float*)Bp;
      float4 v = *reinterpret_cast<const float4*>(Bf + (size_t)(n0 + n) * ldb + kt + kq);
      Bs[kq + 0][n] = v.x;
      Bs[kq + 1][n] = v.y;
      Bs[kq + 2][n] = v.z;
      Bs[kq + 3][n] = v.w;
    } else {
      const int k = tid >> 4, nq = (tid & 15) * 4;
      const float* Bf = (const float*)Bp;
      float4 v = *reinterpret_cast<const float4*>(Bf + (size_t)(kt + k) * ldb + n0 + nq);
      Bs[k][nq + 0] = v.x;
      Bs[k][nq + 1] = v.y;
      Bs[k][nq + 2] = v.z;
      Bs[k][nq + 3] = v.w;
    }
    __syncthreads();
#pragma unroll
    for (int k = 0; k < 16; ++k) {
      float a0 = As[k][ty * 4 + 0], a1 = As[k][ty * 4 + 1];
      float a2 = As[k][ty * 4 + 2], a3 = As[k][ty * 4 + 3];
      float b0 = Bs[k][tx * 4 + 0], b1 = Bs[k][tx * 4 + 1];
      float b2 = Bs[k][tx * 4 + 2], b3 = Bs[k][tx * 4 + 3];
      acc[0][0] += a0 * b0; acc[0][1] += a0 * b1; acc[0][2] += a0 * b2; acc[0][3] += a0 * b3;
      acc[1][0] += a1 * b0; acc[1][1] += a1 * b1; acc[1][2] += a1 * b2; acc[1][3] += a1 * b3;
      acc[2][0] += a2 * b0; acc[2][1] += a2 * b1; acc[2][2] += a2 * b2; acc[2][3] += a2 * b3;
      acc[3][0] += a3 * b0; acc[3][1] += a3 * b1; acc[3][2] += a3 * b2; acc[3][3] += a3 * b3;
    }
    __syncthreads();
  }
#pragma unroll
  for (int i = 0; i < 4; ++i)
#pragma unroll
    for (int j = 0; j < 4; ++j) {
      const size_t row = m0 + ty * 4 + i;
      const int col = n0 + tx * 4 + j;
      float v = acc[i][j];
      if (BIAS) v += bias[col];
      if (CBF16)
        reinterpret_cast<bf16*>(Cp)[row * ldc + col] = __float2bfloat16(v);
      else
        reinterpret_cast<float*>(Cp)[row * ldc + col] = v;
    }
}

// ---------------- bias_comb[j] = sum_d bq[d]*Wuk[j][d] ----------------
__global__ __launch_bounds__(64) void k_biascomb(const float* __restrict__ bq,
                                                 const float* __restrict__ Wuk,
                                                 float* __restrict__ bias_c) {
  int j = blockIdx.x, lane = threadIdx.x;
  float s = 0.f;
  for (int d = lane; d < D_; d += 64) s += bq[d] * Wuk[j * D_ + d];
#pragma unroll
  for (int off = 32; off > 0; off >>= 1) s += __shfl_down(s, off);
  if (lane == 0) bias_c[j] = s;
}

// ---------------- tiled qk + masked softmax ----------------
// grid (32 qtiles, 64 bh); block 256 = 4 waves; wave handles 8 q-rows as
// 2 register-groups of 4. K staged in LDS as two 512-key half-panels
// (pad-20 rows: float4-aligned, conflict-free b128 lane reads).
// Per group: sweep1 = dot + qk write + online max/sum; 64-lane butterfly
// reduce; sweep2 = recomputed dot + aw write. Exact-f32 mask arithmetic.
__global__ __launch_bounds__(256) void k_qk2(const float* __restrict__ q_lat,
                                             const float* __restrict__ k_lat,
                                             const float* __restrict__ maskg,
                                             float* __restrict__ qk_out,
                                             float* __restrict__ aw_out) {
  __shared__ __align__(16) float Kl[512 * 20];   // 40 KB
  __shared__ float mkl[S_];                      // 4 KB
  __shared__ float qls[32 * 16];                 // 2 KB
  const int bh = blockIdx.y, b = bh >> 3, h = bh & 7;
  const int q0 = blockIdx.x * 32;
  const int tid = threadIdx.x, w = tid >> 6, lane = tid & 63;

  for (int i = tid; i < S_; i += 256) mkl[i] = maskg[b * S_ + i];
  if (tid < 128) {
    const int row = tid >> 2, qq = (tid & 3) * 4;
    float4 v = *reinterpret_cast<const float4*>(
        q_lat + (size_t)(b * S_ + q0 + row) * L_ + h * LH_ + qq);
    qls[row * 16 + qq + 0] = v.x; qls[row * 16 + qq + 1] = v.y;
    qls[row * 16 + qq + 2] = v.z; qls[row * 16 + qq + 3] = v.w;
  }
  __syncthreads();

  const size_t obase = (size_t)bh * S_ * S_;

#pragma unroll
  for (int g = 0; g < 2; ++g) {
    const int r0 = w * 8 + g * 4;                // first row of this group
    float qr[4][16];
    float mq[4];
#pragma unroll
    for (int r = 0; r < 4; ++r) {
#pragma unroll
      for (int t = 0; t < 16; ++t) qr[r][t] = qls[(r0 + r) * 16 + t];
      mq[r] = mkl[q0 + r0 + r];
    }
    float mx[4], sm[4];
#pragma unroll
    for (int r = 0; r < 4; ++r) { mx[r] = -INFINITY; sm[r] = 0.f; }

    // ---- sweep 1: qk write + online max/sum ----
    for (int half = 0; half < 2; ++half) {
      __syncthreads();                           // prior Kl reads done
#pragma unroll
      for (int i = 0; i < 8; ++i) {              // stage 512 keys x 16
        const int idx = tid + i * 256;
        const int key = idx >> 2, qq = (idx & 3) * 4;
        float4 v = *reinterpret_cast<const float4*>(
            k_lat + (size_t)(b * S_ + half * 512 + key) * L_ + h * LH_ + qq);
        *reinterpret_cast<float4*>(&Kl[key * 20 + qq]) = v;
      }
      __syncthreads();
#pragma unroll
      for (int c = 0; c < 8; ++c) {
        const int lkey = c * 64 + lane;
        const int key = half * 512 + lkey;
        float kv[16];
#pragma unroll
        for (int t = 0; t < 16; t += 4) {
          float4 v = *reinterpret_cast<const float4*>(&Kl[lkey * 20 + t]);
          kv[t] = v.x; kv[t + 1] = v.y; kv[t + 2] = v.z; kv[t + 3] = v.w;
        }
        const float mk = mkl[key];
#pragma unroll
        for (int r = 0; r < 4; ++r) {
          float d = 0.f;
#pragma unroll
          for (int t = 0; t < 16; ++t) d += qr[r][t] * kv[t];
          d *= 0.25f;
          qk_out[obase + (size_t)(q0 + r0 + r) * S_ + key] = d;
          const float m = fminf(1.f, __fadd_rn(mq[r], mk));
          const float l = __fadd_rn(d, __fmul_rn(m, -1e9f));
          const float nm = fmaxf(mx[r], l);
          sm[r] = sm[r] * __expf(mx[r] - nm) + __expf(l - nm);
          mx[r] = nm;
        }
      }
    }
    // ---- butterfly reduce across 64 lanes ----
#pragma unroll
    for (int r = 0; r < 4; ++r) {
      float m = mx[r], s = sm[r];
#pragma unroll
      for (int st = 1; st < 64; st <<= 1) {
        float om = __shfl_xor(m, st);
        float os = __shfl_xor(s, st);
        float nm = fmaxf(m, om);
        s = s * __expf(m - nm) + os * __expf(om - nm);
        m = nm;
      }
      mx[r] = m;
      sm[r] = 1.f / s;
    }
    // ---- sweep 2: aw write ----
    for (int half = 0; half < 2; ++half) {
      __syncthreads();
#pragma unroll
      for (int i = 0; i < 8; ++i) {
        const int idx = tid + i * 256;
        const int key = idx >> 2, qq = (idx & 3) * 4;
        float4 v = *reinterpret_cast<const float4*>(
            k_lat + (size_t)(b * S_ + half * 512 + key) * L_ + h * LH_ + qq);
        *reinterpret_cast<float4*>(&Kl[key * 20 + qq]) = v;
      }
      __syncthreads();
#pragma unroll
      for (int c = 0; c < 8; ++c) {
        const int lkey = c * 64 + lane;
        const int key = half * 512 + lkey;
        float kv[16];
#pragma unroll
        for (int t = 0; t < 16; t += 4) {
          float4 v = *reinterpret_cast<const float4*>(&Kl[lkey * 20 + t]);
          kv[t] = v.x; kv[t + 1] = v.y; kv[t + 2] = v.z; kv[t + 3] = v.w;
        }
        const float mk = mkl[key];
#pragma unroll
        for (int r = 0; r < 4; ++r) {
          float d = 0.f;
#pragma unroll
          for (int t = 0; t < 16; ++t) d += qr[r][t] * kv[t];
          d *= 0.25f;
          const float m = fminf(1.f, __fadd_rn(mq[r], mk));
          const float l = __fadd_rn(d, __fmul_rn(m, -1e9f));
          aw_out[obase + (size_t)(q0 + r0 + r) * S_ + key] = __expf(l - mx[r]) * sm[r];
        }
      }
    }
  }
}

// ---------------- PV: attn[b,q,h*64+d] = sum_k aw[bh,q,k]*v[b,k,h*64+d] ----
__global__ __launch_bounds__(256) void k_pv(const float* __restrict__ aw,
                                            const bf16* __restrict__ v,
                                            bf16* __restrict__ attn) {
  __shared__ float As[16][65];   // [k][m]
  __shared__ float Bs[16][65];   // [k][n]
  const int bh = blockIdx.y, b = bh >> 3, h = bh & 7;
  const int m0 = blockIdx.x * 64;
  const int tid = threadIdx.x, ty = tid >> 4, tx = tid & 15;
  const float* A = aw + (size_t)bh * S_ * S_;
  float acc[4][4] = {};
  for (int kt = 0; kt < S_; kt += 16) {
    {
      const int m = tid >> 2, kq = (tid & 3) * 4;
      float4 w = *reinterpret_cast<const float4*>(A + (size_t)(m0 + m) * S_ + kt + kq);
      As[kq + 0][m] = w.x; As[kq + 1][m] = w.y; As[kq + 2][m] = w.z; As[kq + 3][m] = w.w;
    }
    {
      const int k = tid >> 4, nq = (tid & 15) * 4;
      ushort4 u = *reinterpret_cast<const ushort4*>(
          reinterpret_cast<const unsigned short*>(v) + (size_t)(b * S_ + kt + k) * D_ + h * HD_ + nq);
      Bs[k][nq + 0] = bfu2f(u.x); Bs[k][nq + 1] = bfu2f(u.y);
      Bs[k][nq + 2] = bfu2f(u.z); Bs[k][nq + 3] = bfu2f(u.w);
    }
    __syncthreads();
#pragma unroll
    for (int k = 0; k < 16; ++k) {
      float a0 = As[k][ty * 4 + 0], a1 = As[k][ty * 4 + 1];
      float a2 = As[k][ty * 4 + 2], a3 = As[k][ty * 4 + 3];
      float b0 = Bs[k][tx * 4 + 0], b1 = Bs[k][tx * 4 + 1];
      float b2 = Bs[k][tx * 4 + 2], b3 = Bs[k][tx * 4 + 3];
      acc[0][0] += a0 * b0; acc[0][1] += a0 * b1; acc[0][2] += a0 * b2; acc[0][3] += a0 * b3;
      acc[1][0] += a1 * b0; acc[1][1] += a1 * b1; acc[1][2] += a1 * b2; acc[1][3] += a1 * b3;
      acc[2][0] += a2 * b0; acc[2][1] += a2 * b1; acc[2][2] += a2 * b2; acc[2][3] += a2 * b3;
      acc[3][0] += a3 * b0; acc[3][1] += a3 * b1; acc[3][2] += a3 * b2; acc[3][3] += a3 * b3;
    }
    __syncthreads();
  }
#pragma unroll
  for (int i = 0; i < 4; ++i)
#pragma unroll
    for (int j = 0; j < 4; ++j)
      attn[(size_t)(b * S_ + m0 + ty * 4 + i) * D_ + h * HD_ + tx * 4 + j] =
          __float2bfloat16(acc[i][j]);
}

extern "C" void kernel_launch(void* const* d_in, const int* in_sizes, int n_in,
                              void* d_out, int out_size, void* d_ws, size_t ws_size,
                              hipStream_t stream) {
  const float* x    = (const float*)d_in[0];
  const float* mask = (const float*)d_in[1];
  const float* Wq   = (const float*)d_in[2];
  const float* bq   = (const float*)d_in[3];
  const float* Wckv = (const float*)d_in[4];
  const float* Wuk  = (const float*)d_in[5];
  const float* Wuv  = (const float*)d_in[6];
  const float* Wo   = (const float*)d_in[7];
  const float* bo   = (const float*)d_in[8];

  // outputs: f32, concatenated (out, attn_weights, qk_values)
  float* out    = (float*)d_out;                          // (B,S,D)
  float* aw_out = out + (size_t)B_ * S_ * D_;             // (B,H,S,S)
  float* qk_out = aw_out + (size_t)B_ * H_ * S_ * S_;     // (B,H,S,S)

  // workspace (~17 MB): Wcomb | bias_c | q_lat | k_lat | v_bf
  // attn_bf aliases [q_lat,k_lat] (dead after k_qk2; sizes match exactly).
  uint8_t* p = (uint8_t*)d_ws;
  auto alloc = [&](size_t bytes) {
    void* r = p;
    p += (bytes + 255) & ~(size_t)255;
    return r;
  };
  float* Wcomb   = (float*)alloc((size_t)512 * 128 * 4);     // 256 KB
  float* bias_c  = (float*)alloc(128 * 4);
  float* q_lat   = (float*)alloc((size_t)8192 * 128 * 4);    // 4.19 MB
  float* k_lat   = (float*)alloc((size_t)8192 * 128 * 4);    // 4.19 MB
  bf16*  v_bf    = (bf16*)alloc((size_t)8192 * 512 * 2);     // 8.39 MB
  bf16*  attn_bf = (bf16*)q_lat;                             // alias, 8.39 MB

  // Wcomb(512x128) = Wq(512x512) @ Wuk^T   [B given as (N=128,K=512) row-major]
  gemm<true, false, false, false><<<dim3(2, 8), 256, 0, stream>>>(
      Wq, 512, Wuk, 512, Wcomb, 128, nullptr, 512);
  // bias_c = bq @ Wuk^T
  k_biascomb<<<128, 64, 0, stream>>>(bq, Wuk, bias_c);
  // q_lat(8192x128) = x @ Wcomb + bias_c
  gemm<false, true, false, false><<<dim3(2, 128), 256, 0, stream>>>(
      x, 512, Wcomb, 128, q_lat, 128, bias_c, 512);
  // k_lat(8192x128) = x @ Wckv
  gemm<false, false, false, false><<<dim3(2, 128), 256, 0, stream>>>(
      x, 512, Wckv, 128, k_lat, 128, nullptr, 512);
  // v(8192x512) = k_lat @ Wuv   (bf16 store)
  gemm<false, false, false, true><<<dim3(8, 128), 256, 0, stream>>>(
      k_lat, 128, Wuv, 512, v_bf, 512, nullptr, 128);
  // qk_values + attn_weights (tiled, f32, exact mask arithmetic)
  k_qk2<<<dim3(32, 64), 256, 0, stream>>>(q_lat, k_lat, mask, qk_out, aw_out);
  // attn = aw @ v   (bf16 store; overwrites q_lat/k_lat region — both dead)
  k_pv<<<dim3(16, 64), 256, 0, stream>>>(aw_out, v_bf, attn_bf);
  // out = attn @ Wo + bo
  gemm<false, true, true, false><<<dim3(8, 128), 256, 0, stream>>>(
      attn_bf, 512, Wo, 512, out, 512, bo, 512);
  (void)in_sizes; (void)n_in; (void)out_size; (void)ws_size;
}

// Round 7
// 563.777 us; speedup vs baseline: 1.8588x; 1.3062x over previous
//
#include <hip/hip_runtime.h>
#include <hip/hip_bf16.h>

typedef __hip_bfloat16 bf16;

#define B_ 8
#define S_ 1024
#define D_ 512
#define H_ 8
#define HD_ 64
#define L_ 128
#define LH_ 16

__device__ __forceinline__ float bfu2f(unsigned short u) {
  unsigned int x = ((unsigned int)u) << 16;
  float f;
  __builtin_memcpy(&f, &x, 4);
  return f;
}

// ---------------- generic tiled f32 GEMM ----------------
// C(MxN) = A(MxK) @ B (+bias). BT: B is row-major (N,K) -> use B[n*ldb+k].
// ABF16: A elements are bf16. CBF16: store bf16. Requires M%64==0, N%64==0, K%16==0.
template<bool BT, bool BIAS, bool ABF16, bool CBF16>
__global__ __launch_bounds__(256) void gemm(const void* __restrict__ Ap, int lda,
                                            const void* __restrict__ Bp, int ldb,
                                            void* __restrict__ Cp, int ldc,
                                            const float* __restrict__ bias, int K) {
  __shared__ float As[16][65];   // [k][m]
  __shared__ float Bs[16][65];   // [k][n]
  const int tid = threadIdx.x;
  const int m0 = blockIdx.y * 64, n0 = blockIdx.x * 64;
  const int ty = tid >> 4, tx = tid & 15;
  float acc[4][4] = {};
  for (int kt = 0; kt < K; kt += 16) {
    // stage A: 64 rows x 16 k
    {
      const int m = tid >> 2, kq = (tid & 3) * 4;
      if (ABF16) {
        const bf16* A = (const bf16*)Ap;
        ushort4 u = *reinterpret_cast<const ushort4*>(
            reinterpret_cast<const unsigned short*>(A) + (size_t)(m0 + m) * lda + kt + kq);
        As[kq + 0][m] = bfu2f(u.x);
        As[kq + 1][m] = bfu2f(u.y);
        As[kq + 2][m] = bfu2f(u.z);
        As[kq + 3][m] = bfu2f(u.w);
      } else {
        const float* A = (const float*)Ap;
        float4 v = *reinterpret_cast<const float4*>(A + (size_t)(m0 + m) * lda + kt + kq);
        As[kq + 0][m] = v.x;
        As[kq + 1][m] = v.y;
        As[kq + 2][m] = v.z;
        As[kq + 3][m] = v.w;
      }
    }
    // stage B: 16 k x 64 n
    if (BT) {
      const int n = tid >> 2, kq = (tid & 3) * 4;
      const float* Bf = (const float*)Bp;
      float4 v = *reinterpret_cast<const float4*>(Bf + (size_t)(n0 + n) * ldb + kt + kq);
      Bs[kq + 0][n] = v.x;
      Bs[kq + 1][n] = v.y;
      Bs[kq + 2][n] = v.z;
      Bs[kq + 3][n] = v.w;
    } else {
      const int k = tid >> 4, nq = (tid & 15) * 4;
      const float* Bf = (const float*)Bp;
      float4 v = *reinterpret_cast<const float4*>(Bf + (size_t)(kt + k) * ldb + n0 + nq);
      Bs[k][nq + 0] = v.x;
      Bs[k][nq + 1] = v.y;
      Bs[k][nq + 2] = v.z;
      Bs[k][nq + 3] = v.w;
    }
    __syncthreads();
#pragma unroll
    for (int k = 0; k < 16; ++k) {
      float a0 = As[k][ty * 4 + 0], a1 = As[k][ty * 4 + 1];
      float a2 = As[k][ty * 4 + 2], a3 = As[k][ty * 4 + 3];
      float b0 = Bs[k][tx * 4 + 0], b1 = Bs[k][tx * 4 + 1];
      float b2 = Bs[k][tx * 4 + 2], b3 = Bs[k][tx * 4 + 3];
      acc[0][0] += a0 * b0; acc[0][1] += a0 * b1; acc[0][2] += a0 * b2; acc[0][3] += a0 * b3;
      acc[1][0] += a1 * b0; acc[1][1] += a1 * b1; acc[1][2] += a1 * b2; acc[1][3] += a1 * b3;
      acc[2][0] += a2 * b0; acc[2][1] += a2 * b1; acc[2][2] += a2 * b2; acc[2][3] += a2 * b3;
      acc[3][0] += a3 * b0; acc[3][1] += a3 * b1; acc[3][2] += a3 * b2; acc[3][3] += a3 * b3;
    }
    __syncthreads();
  }
#pragma unroll
  for (int i = 0; i < 4; ++i)
#pragma unroll
    for (int j = 0; j < 4; ++j) {
      const size_t row = m0 + ty * 4 + i;
      const int col = n0 + tx * 4 + j;
      float v = acc[i][j];
      if (BIAS) v += bias[col];
      if (CBF16)
        reinterpret_cast<bf16*>(Cp)[row * ldc + col] = __float2bfloat16(v);
      else
        reinterpret_cast<float*>(Cp)[row * ldc + col] = v;
    }
}

// ---------------- bias_comb[j] = sum_d bq[d]*Wuk[j][d] ----------------
__global__ __launch_bounds__(64) void k_biascomb(const float* __restrict__ bq,
                                                 const float* __restrict__ Wuk,
                                                 float* __restrict__ bias_c) {
  int j = blockIdx.x, lane = threadIdx.x;
  float s = 0.f;
  for (int d = lane; d < D_; d += 64) s += bq[d] * Wuk[j * D_ + d];
#pragma unroll
  for (int off = 32; off > 0; off >>= 1) s += __shfl_down(s, off);
  if (lane == 0) bias_c[j] = s;
}

// ---------------- tiled qk + masked softmax, v3 ----------------
// grid (128 qtiles of 8 rows, 64 bh); block 256 = 4 waves; wave owns 2 q-rows.
// K staged in LDS per 512-key half (pad-20 rows). Single compute pass:
// dot -> qk write -> logits kept in regs (l[2][16]). Then register-tree +
// 64-lane butterfly max/sum, 1 exp per element, aw written from regs.
// Exact-f32 mask arithmetic preserved (fminf/fadd/fmul, no fma contraction).
__global__ __launch_bounds__(256) void k_qk3(const float* __restrict__ q_lat,
                                             const float* __restrict__ k_lat,
                                             const float* __restrict__ maskg,
                                             float* __restrict__ qk_out,
                                             float* __restrict__ aw_out) {
  __shared__ __align__(16) float Kl[512 * 20];   // 40 KB
  __shared__ float mkl[S_];                      // 4 KB
  __shared__ float qls[8 * 16];                  // 0.5 KB
  const int bh = blockIdx.y, b = bh >> 3, h = bh & 7;
  const int q0 = blockIdx.x * 8;
  const int tid = threadIdx.x, w = tid >> 6, lane = tid & 63;

  for (int i = tid; i < S_; i += 256) mkl[i] = maskg[b * S_ + i];
  if (tid < 32) {
    const int row = tid >> 2, qq = (tid & 3) * 4;
    float4 v = *reinterpret_cast<const float4*>(
        q_lat + (size_t)(b * S_ + q0 + row) * L_ + h * LH_ + qq);
    qls[row * 16 + qq + 0] = v.x; qls[row * 16 + qq + 1] = v.y;
    qls[row * 16 + qq + 2] = v.z; qls[row * 16 + qq + 3] = v.w;
  }
  __syncthreads();

  const int r0 = w * 2;                          // wave's first row (0..6)
  float qr[2][16], mq[2];
#pragma unroll
  for (int r = 0; r < 2; ++r) {
#pragma unroll
    for (int t = 0; t < 16; ++t) qr[r][t] = qls[(r0 + r) * 16 + t];
    mq[r] = mkl[q0 + r0 + r];
  }
  const size_t obase = (size_t)bh * S_ * S_;
  float l[2][16];

  // ---- single compute pass: dots + qk writes, logits to registers ----
#pragma unroll
  for (int half = 0; half < 2; ++half) {
    if (half) __syncthreads();                   // all waves done reading Kl
#pragma unroll
    for (int i = 0; i < 8; ++i) {                // stage 512 keys x 16
      const int idx = tid + i * 256;
      const int key = idx >> 2, qq = (idx & 3) * 4;
      float4 v = *reinterpret_cast<const float4*>(
          k_lat + (size_t)(b * S_ + half * 512 + key) * L_ + h * LH_ + qq);
      *reinterpret_cast<float4*>(&Kl[key * 20 + qq]) = v;
    }
    __syncthreads();
#pragma unroll
    for (int c = 0; c < 8; ++c) {
      const int lkey = c * 64 + lane;
      const int key = half * 512 + lkey;
      float kv[16];
#pragma unroll
      for (int t = 0; t < 16; t += 4) {
        float4 v = *reinterpret_cast<const float4*>(&Kl[lkey * 20 + t]);
        kv[t] = v.x; kv[t + 1] = v.y; kv[t + 2] = v.z; kv[t + 3] = v.w;
      }
      const float mk = mkl[key];
#pragma unroll
      for (int r = 0; r < 2; ++r) {
        float d = 0.f;
#pragma unroll
        for (int t = 0; t < 16; ++t) d += qr[r][t] * kv[t];
        d *= 0.25f;
        qk_out[obase + (size_t)(q0 + r0 + r) * S_ + key] = d;
        const float m = fminf(1.f, __fadd_rn(mq[r], mk));
        l[r][half * 8 + c] = __fadd_rn(d, __fmul_rn(m, -1e9f));
      }
    }
  }

  // ---- softmax from registers: tree max, butterfly, 1 exp/elem, sum ----
#pragma unroll
  for (int r = 0; r < 2; ++r) {
    float M = l[r][0];
#pragma unroll
    for (int idx = 1; idx < 16; ++idx) M = fmaxf(M, l[r][idx]);
#pragma unroll
    for (int st = 1; st < 64; st <<= 1) M = fmaxf(M, __shfl_xor(M, st));
    float s = 0.f;
#pragma unroll
    for (int idx = 0; idx < 16; ++idx) {
      const float e = __expf(l[r][idx] - M);
      l[r][idx] = e;
      s += e;
    }
#pragma unroll
    for (int st = 1; st < 64; st <<= 1) s += __shfl_xor(s, st);
    const float inv = 1.f / s;
    const size_t orow = obase + (size_t)(q0 + r0 + r) * S_;
#pragma unroll
    for (int idx = 0; idx < 16; ++idx)
      aw_out[orow + (idx >> 3) * 512 + (idx & 7) * 64 + lane] = l[r][idx] * inv;
  }
}

// ---------------- PV: attn[b,q,h*64+d] = sum_k aw[bh,q,k]*v[b,k,h*64+d] ----
__global__ __launch_bounds__(256) void k_pv(const float* __restrict__ aw,
                                            const bf16* __restrict__ v,
                                            bf16* __restrict__ attn) {
  __shared__ float As[16][65];   // [k][m]
  __shared__ float Bs[16][65];   // [k][n]
  const int bh = blockIdx.y, b = bh >> 3, h = bh & 7;
  const int m0 = blockIdx.x * 64;
  const int tid = threadIdx.x, ty = tid >> 4, tx = tid & 15;
  const float* A = aw + (size_t)bh * S_ * S_;
  float acc[4][4] = {};
  for (int kt = 0; kt < S_; kt += 16) {
    {
      const int m = tid >> 2, kq = (tid & 3) * 4;
      float4 w = *reinterpret_cast<const float4*>(A + (size_t)(m0 + m) * S_ + kt + kq);
      As[kq + 0][m] = w.x; As[kq + 1][m] = w.y; As[kq + 2][m] = w.z; As[kq + 3][m] = w.w;
    }
    {
      const int k = tid >> 4, nq = (tid & 15) * 4;
      ushort4 u = *reinterpret_cast<const ushort4*>(
          reinterpret_cast<const unsigned short*>(v) + (size_t)(b * S_ + kt + k) * D_ + h * HD_ + nq);
      Bs[k][nq + 0] = bfu2f(u.x); Bs[k][nq + 1] = bfu2f(u.y);
      Bs[k][nq + 2] = bfu2f(u.z); Bs[k][nq + 3] = bfu2f(u.w);
    }
    __syncthreads();
#pragma unroll
    for (int k = 0; k < 16; ++k) {
      float a0 = As[k][ty * 4 + 0], a1 = As[k][ty * 4 + 1];
      float a2 = As[k][ty * 4 + 2], a3 = As[k][ty * 4 + 3];
      float b0 = Bs[k][tx * 4 + 0], b1 = Bs[k][tx * 4 + 1];
      float b2 = Bs[k][tx * 4 + 2], b3 = Bs[k][tx * 4 + 3];
      acc[0][0] += a0 * b0; acc[0][1] += a0 * b1; acc[0][2] += a0 * b2; acc[0][3] += a0 * b3;
      acc[1][0] += a1 * b0; acc[1][1] += a1 * b1; acc[1][2] += a1 * b2; acc[1][3] += a1 * b3;
      acc[2][0] += a2 * b0; acc[2][1] += a2 * b1; acc[2][2] += a2 * b2; acc[2][3] += a2 * b3;
      acc[3][0] += a3 * b0; acc[3][1] += a3 * b1; acc[3][2] += a3 * b2; acc[3][3] += a3 * b3;
    }
    __syncthreads();
  }
#pragma unroll
  for (int i = 0; i < 4; ++i)
#pragma unroll
    for (int j = 0; j < 4; ++j)
      attn[(size_t)(b * S_ + m0 + ty * 4 + i) * D_ + h * HD_ + tx * 4 + j] =
          __float2bfloat16(acc[i][j]);
}

extern "C" void kernel_launch(void* const* d_in, const int* in_sizes, int n_in,
                              void* d_out, int out_size, void* d_ws, size_t ws_size,
                              hipStream_t stream) {
  const float* x    = (const float*)d_in[0];
  const float* mask = (const float*)d_in[1];
  const float* Wq   = (const float*)d_in[2];
  const float* bq   = (const float*)d_in[3];
  const float* Wckv = (const float*)d_in[4];
  const float* Wuk  = (const float*)d_in[5];
  const float* Wuv  = (const float*)d_in[6];
  const float* Wo   = (const float*)d_in[7];
  const float* bo   = (const float*)d_in[8];

  // outputs: f32, concatenated (out, attn_weights, qk_values)
  float* out    = (float*)d_out;                          // (B,S,D)
  float* aw_out = out + (size_t)B_ * S_ * D_;             // (B,H,S,S)
  float* qk_out = aw_out + (size_t)B_ * H_ * S_ * S_;     // (B,H,S,S)

  // workspace (~17 MB): Wcomb | bias_c | q_lat | k_lat | v_bf
  // attn_bf aliases [q_lat,k_lat] (dead after k_qk3; sizes match exactly).
  uint8_t* p = (uint8_t*)d_ws;
  auto alloc = [&](size_t bytes) {
    void* r = p;
    p += (bytes + 255) & ~(size_t)255;
    return r;
  };
  float* Wcomb   = (float*)alloc((size_t)512 * 128 * 4);     // 256 KB
  float* bias_c  = (float*)alloc(128 * 4);
  float* q_lat   = (float*)alloc((size_t)8192 * 128 * 4);    // 4.19 MB
  float* k_lat   = (float*)alloc((size_t)8192 * 128 * 4);    // 4.19 MB
  bf16*  v_bf    = (bf16*)alloc((size_t)8192 * 512 * 2);     // 8.39 MB
  bf16*  attn_bf = (bf16*)q_lat;                             // alias, 8.39 MB

  // Wcomb(512x128) = Wq(512x512) @ Wuk^T   [B given as (N=128,K=512) row-major]
  gemm<true, false, false, false><<<dim3(2, 8), 256, 0, stream>>>(
      Wq, 512, Wuk, 512, Wcomb, 128, nullptr, 512);
  // bias_c = bq @ Wuk^T
  k_biascomb<<<128, 64, 0, stream>>>(bq, Wuk, bias_c);
  // q_lat(8192x128) = x @ Wcomb + bias_c
  gemm<false, true, false, false><<<dim3(2, 128), 256, 0, stream>>>(
      x, 512, Wcomb, 128, q_lat, 128, bias_c, 512);
  // k_lat(8192x128) = x @ Wckv
  gemm<false, false, false, false><<<dim3(2, 128), 256, 0, stream>>>(
      x, 512, Wckv, 128, k_lat, 128, nullptr, 512);
  // v(8192x512) = k_lat @ Wuv   (bf16 store)
  gemm<false, false, false, true><<<dim3(8, 128), 256, 0, stream>>>(
      k_lat, 128, Wuv, 512, v_bf, 512, nullptr, 128);
  // qk_values + attn_weights (register-resident logits, 1 exp/elem)
  k_qk3<<<dim3(128, 64), 256, 0, stream>>>(q_lat, k_lat, mask, qk_out, aw_out);
  // attn = aw @ v   (bf16 store; overwrites q_lat/k_lat region — both dead)
  k_pv<<<dim3(16, 64), 256, 0, stream>>>(aw_out, v_bf, attn_bf);
  // out = attn @ Wo + bo
  gemm<false, true, true, false><<<dim3(8, 128), 256, 0, stream>>>(
      attn_bf, 512, Wo, 512, out, 512, bo, 512);
  (void)in_sizes; (void)n_in; (void)out_size; (void)ws_size;
}

// Round 8
// 374.102 us; speedup vs baseline: 2.8012x; 1.5070x over previous
//
#include <hip/hip_runtime.h>
#include <hip/hip_bf16.h>

typedef __hip_bfloat16 bf16;
typedef __attribute__((ext_vector_type(8))) short short8;
typedef __attribute__((ext_vector_type(4))) float f32x4;

#define B_ 8
#define S_ 1024
#define D_ 512
#define H_ 8
#define HD_ 64
#define L_ 128
#define LH_ 16

__device__ __forceinline__ float bfu2f(unsigned short u) {
  unsigned int x = ((unsigned int)u) << 16;
  float f;
  __builtin_memcpy(&f, &x, 4);
  return f;
}
__device__ __forceinline__ unsigned short bfbits(float f) {
  bf16 h = __float2bfloat16(f);
  unsigned short u;
  __builtin_memcpy(&u, &h, 2);
  return u;
}
__device__ __forceinline__ f32x4 mfma_bf16(short8 a, short8 b, f32x4 c) {
  return __builtin_amdgcn_mfma_f32_16x16x32_bf16(a, b, c, 0, 0, 0);
}

// ---------------- generic tiled f32 GEMM (GREEN since r5) ----------------
// C(MxN) = A(MxK) @ B (+bias). BT: B is row-major (N,K) -> use B[n*ldb+k].
// ABF16: A elements are bf16. CBF16: store bf16. Requires M%64==0, N%64==0, K%16==0.
template<bool BT, bool BIAS, bool ABF16, bool CBF16>
__global__ __launch_bounds__(256) void gemm(const void* __restrict__ Ap, int lda,
                                            const void* __restrict__ Bp, int ldb,
                                            void* __restrict__ Cp, int ldc,
                                            const float* __restrict__ bias, int K) {
  __shared__ float As[16][65];   // [k][m]
  __shared__ float Bs[16][65];   // [k][n]
  const int tid = threadIdx.x;
  const int m0 = blockIdx.y * 64, n0 = blockIdx.x * 64;
  const int ty = tid >> 4, tx = tid & 15;
  float acc[4][4] = {};
  for (int kt = 0; kt < K; kt += 16) {
    {
      const int m = tid >> 2, kq = (tid & 3) * 4;
      if (ABF16) {
        const bf16* A = (const bf16*)Ap;
        ushort4 u = *reinterpret_cast<const ushort4*>(
            reinterpret_cast<const unsigned short*>(A) + (size_t)(m0 + m) * lda + kt + kq);
        As[kq + 0][m] = bfu2f(u.x);
        As[kq + 1][m] = bfu2f(u.y);
        As[kq + 2][m] = bfu2f(u.z);
        As[kq + 3][m] = bfu2f(u.w);
      } else {
        const float* A = (const float*)Ap;
        float4 v = *reinterpret_cast<const float4*>(A + (size_t)(m0 + m) * lda + kt + kq);
        As[kq + 0][m] = v.x;
        As[kq + 1][m] = v.y;
        As[kq + 2][m] = v.z;
        As[kq + 3][m] = v.w;
      }
    }
    if (BT) {
      const int n = tid >> 2, kq = (tid & 3) * 4;
      const float* Bf = (const float*)Bp;
      float4 v = *reinterpret_cast<const float4*>(Bf + (size_t)(n0 + n) * ldb + kt + kq);
      Bs[kq + 0][n] = v.x;
      Bs[kq + 1][n] = v.y;
      Bs[kq + 2][n] = v.z;
      Bs[kq + 3][n] = v.w;
    } else {
      const int k = tid >> 4, nq = (tid & 15) * 4;
      const float* Bf = (const float*)Bp;
      float4 v = *reinterpret_cast<const float4*>(Bf + (size_t)(kt + k) * ldb + n0 + nq);
      Bs[k][nq + 0] = v.x;
      Bs[k][nq + 1] = v.y;
      Bs[k][nq + 2] = v.z;
      Bs[k][nq + 3] = v.w;
    }
    __syncthreads();
#pragma unroll
    for (int k = 0; k < 16; ++k) {
      float a0 = As[k][ty * 4 + 0], a1 = As[k][ty * 4 + 1];
      float a2 = As[k][ty * 4 + 2], a3 = As[k][ty * 4 + 3];
      float b0 = Bs[k][tx * 4 + 0], b1 = Bs[k][tx * 4 + 1];
      float b2 = Bs[k][tx * 4 + 2], b3 = Bs[k][tx * 4 + 3];
      acc[0][0] += a0 * b0; acc[0][1] += a0 * b1; acc[0][2] += a0 * b2; acc[0][3] += a0 * b3;
      acc[1][0] += a1 * b0; acc[1][1] += a1 * b1; acc[1][2] += a1 * b2; acc[1][3] += a1 * b3;
      acc[2][0] += a2 * b0; acc[2][1] += a2 * b1; acc[2][2] += a2 * b2; acc[2][3] += a2 * b3;
      acc[3][0] += a3 * b0; acc[3][1] += a3 * b1; acc[3][2] += a3 * b2; acc[3][3] += a3 * b3;
    }
    __syncthreads();
  }
#pragma unroll
  for (int i = 0; i < 4; ++i)
#pragma unroll
    for (int j = 0; j < 4; ++j) {
      const size_t row = m0 + ty * 4 + i;
      const int col = n0 + tx * 4 + j;
      float v = acc[i][j];
      if (BIAS) v += bias[col];
      if (CBF16)
        reinterpret_cast<bf16*>(Cp)[row * ldc + col] = __float2bfloat16(v);
      else
        reinterpret_cast<float*>(Cp)[row * ldc + col] = v;
    }
}

// ---------------- f32 transpose (RxC -> CxR), f32 out ----------------
__global__ __launch_bounds__(256) void k_tr_f32(const float* __restrict__ in,
                                                float* __restrict__ out, int R, int C) {
  __shared__ float t[32][33];
  int tx = threadIdx.x & 31, ty = threadIdx.x >> 5;
  int r0 = blockIdx.y * 32, c0 = blockIdx.x * 32;
#pragma unroll
  for (int i = 0; i < 32; i += 8)
    t[ty + i][tx] = in[(size_t)(r0 + ty + i) * C + c0 + tx];
  __syncthreads();
#pragma unroll
  for (int i = 0; i < 32; i += 8)
    out[(size_t)(c0 + ty + i) * R + r0 + tx] = t[tx][ty + i];
}

// ---------------- f32 (RxC) -> bf16 transposed (CxR) ----------------
__global__ __launch_bounds__(256) void k_tr_f32_bf16(const float* __restrict__ in,
                                                     bf16* __restrict__ out,
                                                     int R, int C) {
  __shared__ float t[32][33];
  int tx = threadIdx.x & 31, ty = threadIdx.x >> 5;
  int r0 = blockIdx.y * 32, c0 = blockIdx.x * 32;
#pragma unroll
  for (int i = 0; i < 32; i += 8)
    t[ty + i][tx] = in[(size_t)(r0 + ty + i) * C + c0 + tx];
  __syncthreads();
#pragma unroll
  for (int i = 0; i < 32; i += 8)
    out[(size_t)(c0 + ty + i) * R + r0 + tx] = __float2bfloat16(t[tx][ty + i]);
}

// ---------------- copy Wckv into cols 128..255 of wcat ----------------
__global__ __launch_bounds__(256) void k_copy_wckv(const float* __restrict__ Wckv,
                                                   float* __restrict__ wcat) {
  int idx = blockIdx.x * 256 + threadIdx.x;   // 0..65535
  int k = idx >> 7, n = idx & 127;
  wcat[k * 256 + 128 + n] = Wckv[k * 128 + n];
}

// -------- bias_c[j] = sum_d bq[d]*Wuk[j][d] for j<128, else 0 --------
__global__ __launch_bounds__(64) void k_biascomb(const float* __restrict__ bq,
                                                 const float* __restrict__ Wuk,
                                                 float* __restrict__ bias_c) {
  int j = blockIdx.x, lane = threadIdx.x;
  if (j >= L_) { if (lane == 0) bias_c[j] = 0.f; return; }
  float s = 0.f;
  for (int d = lane; d < D_; d += 64) s += bq[d] * Wuk[j * D_ + d];
#pragma unroll
  for (int off = 32; off > 0; off >>= 1) s += __shfl_down(s, off);
  if (lane == 0) bias_c[j] = s;
}

// ---------------- tiled qk + masked softmax (GREEN since r7) ----------------
// xw layout: (B*S, 256) f32 = [q_lat | k_lat]. Wave owns 2 q-rows; logits in regs.
__global__ __launch_bounds__(256) void k_qk3(const float* __restrict__ xw,
                                             const float* __restrict__ maskg,
                                             float* __restrict__ qk_out,
                                             float* __restrict__ aw_out) {
  __shared__ __align__(16) float Kl[512 * 20];   // 40 KB
  __shared__ float mkl[S_];                      // 4 KB
  __shared__ float qls[8 * 16];                  // 0.5 KB
  const int bh = blockIdx.y, b = bh >> 3, h = bh & 7;
  const int q0 = blockIdx.x * 8;
  const int tid = threadIdx.x, w = tid >> 6, lane = tid & 63;

  for (int i = tid; i < S_; i += 256) mkl[i] = maskg[b * S_ + i];
  if (tid < 32) {
    const int row = tid >> 2, qq = (tid & 3) * 4;
    float4 v = *reinterpret_cast<const float4*>(
        xw + (size_t)(b * S_ + q0 + row) * 256 + h * LH_ + qq);
    qls[row * 16 + qq + 0] = v.x; qls[row * 16 + qq + 1] = v.y;
    qls[row * 16 + qq + 2] = v.z; qls[row * 16 + qq + 3] = v.w;
  }
  __syncthreads();

  const int r0 = w * 2;
  float qr[2][16], mq[2];
#pragma unroll
  for (int r = 0; r < 2; ++r) {
#pragma unroll
    for (int t = 0; t < 16; ++t) qr[r][t] = qls[(r0 + r) * 16 + t];
    mq[r] = mkl[q0 + r0 + r];
  }
  const size_t obase = (size_t)bh * S_ * S_;
  float l[2][16];

#pragma unroll
  for (int half = 0; half < 2; ++half) {
    if (half) __syncthreads();
#pragma unroll
    for (int i = 0; i < 8; ++i) {
      const int idx = tid + i * 256;
      const int key = idx >> 2, qq = (idx & 3) * 4;
      float4 v = *reinterpret_cast<const float4*>(
          xw + (size_t)(b * S_ + half * 512 + key) * 256 + 128 + h * LH_ + qq);
      *reinterpret_cast<float4*>(&Kl[key * 20 + qq]) = v;
    }
    __syncthreads();
#pragma unroll
    for (int c = 0; c < 8; ++c) {
      const int lkey = c * 64 + lane;
      const int key = half * 512 + lkey;
      float kv[16];
#pragma unroll
      for (int t = 0; t < 16; t += 4) {
        float4 v = *reinterpret_cast<const float4*>(&Kl[lkey * 20 + t]);
        kv[t] = v.x; kv[t + 1] = v.y; kv[t + 2] = v.z; kv[t + 3] = v.w;
      }
      const float mk = mkl[key];
#pragma unroll
      for (int r = 0; r < 2; ++r) {
        float d = 0.f;
#pragma unroll
        for (int t = 0; t < 16; ++t) d += qr[r][t] * kv[t];
        d *= 0.25f;
        qk_out[obase + (size_t)(q0 + r0 + r) * S_ + key] = d;
        const float m = fminf(1.f, __fadd_rn(mq[r], mk));
        l[r][half * 8 + c] = __fadd_rn(d, __fmul_rn(m, -1e9f));
      }
    }
  }

#pragma unroll
  for (int r = 0; r < 2; ++r) {
    float M = l[r][0];
#pragma unroll
    for (int idx = 1; idx < 16; ++idx) M = fmaxf(M, l[r][idx]);
#pragma unroll
    for (int st = 1; st < 64; st <<= 1) M = fmaxf(M, __shfl_xor(M, st));
    float s = 0.f;
#pragma unroll
    for (int idx = 0; idx < 16; ++idx) {
      const float e = __expf(l[r][idx] - M);
      l[r][idx] = e;
      s += e;
    }
#pragma unroll
    for (int st = 1; st < 64; st <<= 1) s += __shfl_xor(s, st);
    const float inv = 1.f / s;
    const size_t orow = obase + (size_t)(q0 + r0 + r) * S_;
#pragma unroll
    for (int idx = 0; idx < 16; ++idx)
      aw_out[orow + (idx >> 3) * 512 + (idx & 7) * 64 + lane] = l[r][idx] * inv;
  }
}

// ---------------- PV via MFMA ----------------
// attn(b,q,h*64+d) = sum_k aw[bh,q,k] * V[k,d];  B-operand from vt (V^T, 512x8192).
// Block: 128 q-rows x 64 d per (qtile, bh); 4 waves, each 32q x 64d = 2x4 frags.
// m97/m89 conventions: A staged [row][k] pad-40, av=sA[(mf*16+l15)*40+l4*8];
// C/D: col=lane&15, row=(lane>>4)*4+j.
__global__ __launch_bounds__(256) void k_pv_mfma(const float* __restrict__ aw,
                                                 const bf16* __restrict__ vt,
                                                 bf16* __restrict__ attn) {
  __shared__ __align__(16) short Pl[128 * 40];   // 10 KB
  __shared__ __align__(16) short Vl[64 * 40];    // 5 KB
  const int bh = blockIdx.y, b = bh >> 3, h = bh & 7;
  const int q0 = blockIdx.x * 128;
  const int tid = threadIdx.x, w = tid >> 6, lane = tid & 63;
  const int l15 = lane & 15, l4 = lane >> 4;
  const float* A = aw + (size_t)bh * S_ * S_;
  const unsigned short* vtp =
      reinterpret_cast<const unsigned short*>(vt) + (size_t)h * 64 * 8192 + b * S_;
  f32x4 acc[2][4] = {};
  for (int kt = 0; kt < 32; ++kt) {
    __syncthreads();                              // prior frag reads done
    {                                             // stage P: 128 rows x 32 k
      const int r = tid >> 1, half = (tid & 1) * 16;
      const float* src = A + (size_t)(q0 + r) * S_ + kt * 32 + half;
      short* dst = &Pl[r * 40 + half];
#pragma unroll
      for (int i = 0; i < 4; ++i) {
        float4 v = *reinterpret_cast<const float4*>(src + i * 4);
        ushort4 o = { bfbits(v.x), bfbits(v.y), bfbits(v.z), bfbits(v.w) };
        *reinterpret_cast<ushort4*>(dst + i * 4) = o;
      }
    }
    if (tid < 64) {                               // stage V^T: 64 d x 32 k
      const unsigned short* src = vtp + (size_t)tid * 8192 + kt * 32;
      *reinterpret_cast<uint4*>(&Vl[tid * 40 + 0])  = *reinterpret_cast<const uint4*>(src + 0);
      *reinterpret_cast<uint4*>(&Vl[tid * 40 + 8])  = *reinterpret_cast<const uint4*>(src + 8);
      *reinterpret_cast<uint4*>(&Vl[tid * 40 + 16]) = *reinterpret_cast<const uint4*>(src + 16);
      *reinterpret_cast<uint4*>(&Vl[tid * 40 + 24]) = *reinterpret_cast<const uint4*>(src + 24);
    }
    __syncthreads();
    short8 av[2], bv[4];
#pragma unroll
    for (int mf = 0; mf < 2; ++mf)
      av[mf] = *reinterpret_cast<const short8*>(&Pl[(w * 32 + mf * 16 + l15) * 40 + l4 * 8]);
#pragma unroll
    for (int nf = 0; nf < 4; ++nf)
      bv[nf] = *reinterpret_cast<const short8*>(&Vl[(nf * 16 + l15) * 40 + l4 * 8]);
#pragma unroll
    for (int mf = 0; mf < 2; ++mf)
#pragma unroll
      for (int nf = 0; nf < 4; ++nf)
        acc[mf][nf] = mfma_bf16(av[mf], bv[nf], acc[mf][nf]);
  }
#pragma unroll
  for (int mf = 0; mf < 2; ++mf)
#pragma unroll
    for (int nf = 0; nf < 4; ++nf)
#pragma unroll
      for (int j = 0; j < 4; ++j)
        attn[(size_t)(b * S_ + q0 + w * 32 + mf * 16 + l4 * 4 + j) * 512 +
             h * 64 + nf * 16 + l15] = __float2bfloat16(acc[mf][nf][j]);
}

// ---------------- out = attn_bf @ woT^T + bo via MFMA ----------------
// C(8192x512) f32; A attn_bf (8192x512 bf16); Bt = woT (512x512 bf16, [n][k]).
__global__ __launch_bounds__(256) void gemm_mfma_out(const bf16* __restrict__ Ab,
                                                     const bf16* __restrict__ Bt,
                                                     float* __restrict__ C,
                                                     const float* __restrict__ bias) {
  __shared__ __align__(16) short sA[128 * 40];   // 10 KB
  __shared__ __align__(16) short sB[128 * 40];   // 10 KB
  const int tid = threadIdx.x, lane = tid & 63;
  const int l15 = lane & 15, l4 = lane >> 4;
  const int wm = ((tid >> 6) >> 1) * 64, wn = ((tid >> 6) & 1) * 64;
  const size_t bn0 = (size_t)blockIdx.x * 128, bm0 = (size_t)blockIdx.y * 128;
  const unsigned short* A = reinterpret_cast<const unsigned short*>(Ab);
  const unsigned short* Bu = reinterpret_cast<const unsigned short*>(Bt);
  f32x4 acc[4][4] = {};
  for (int kt = 0; kt < 512; kt += 32) {
    __syncthreads();
#pragma unroll
    for (int i = 0; i < 2; ++i) {
      const int c = tid + i * 256;
      const int row = c >> 2, k8 = (c & 3) * 8;
      *reinterpret_cast<uint4*>(&sA[row * 40 + k8]) =
          *reinterpret_cast<const uint4*>(A + (bm0 + row) * 512 + kt + k8);
      *reinterpret_cast<uint4*>(&sB[row * 40 + k8]) =
          *reinterpret_cast<const uint4*>(Bu + (bn0 + row) * 512 + kt + k8);
    }
    __syncthreads();
    short8 av[4], bv[4];
#pragma unroll
    for (int mf = 0; mf < 4; ++mf)
      av[mf] = *reinterpret_cast<const short8*>(&sA[(wm + mf * 16 + l15) * 40 + l4 * 8]);
#pragma unroll
    for (int nf = 0; nf < 4; ++nf)
      bv[nf] = *reinterpret_cast<const short8*>(&sB[(wn + nf * 16 + l15) * 40 + l4 * 8]);
#pragma unroll
    for (int mf = 0; mf < 4; ++mf)
#pragma unroll
      for (int nf = 0; nf < 4; ++nf)
        acc[mf][nf] = mfma_bf16(av[mf], bv[nf], acc[mf][nf]);
  }
#pragma unroll
  for (int mf = 0; mf < 4; ++mf)
#pragma unroll
    for (int nf = 0; nf < 4; ++nf)
#pragma unroll
      for (int j = 0; j < 4; ++j) {
        const size_t row = bm0 + wm + mf * 16 + l4 * 4 + j;
        const int col = bn0 + wn + nf * 16 + l15;
        C[row * 512 + col] = acc[mf][nf][j] + bias[col];
      }
}

extern "C" void kernel_launch(void* const* d_in, const int* in_sizes, int n_in,
                              void* d_out, int out_size, void* d_ws, size_t ws_size,
                              hipStream_t stream) {
  const float* x    = (const float*)d_in[0];
  const float* mask = (const float*)d_in[1];
  const float* Wq   = (const float*)d_in[2];
  const float* bq   = (const float*)d_in[3];
  const float* Wckv = (const float*)d_in[4];
  const float* Wuk  = (const float*)d_in[5];
  const float* Wuv  = (const float*)d_in[6];
  const float* Wo   = (const float*)d_in[7];
  const float* bo   = (const float*)d_in[8];

  float* out    = (float*)d_out;                          // (B,S,D)
  float* aw_out = out + (size_t)B_ * S_ * D_;             // (B,H,S,S)
  float* qk_out = aw_out + (size_t)B_ * H_ * S_ * S_;     // (B,H,S,S)

  // workspace ~17.3 MB; attn_bf aliases xw (dead after k_qk3 / vt GEMM)
  uint8_t* p = (uint8_t*)d_ws;
  auto alloc = [&](size_t bytes) {
    void* r = p;
    p += (bytes + 255) & ~(size_t)255;
    return r;
  };
  float* wcat    = (float*)alloc((size_t)512 * 256 * 4);    // 512 KB [Wcomb|Wckv]
  float* bias_c  = (float*)alloc(256 * 4);
  float* wuvT_f  = (float*)alloc((size_t)512 * 128 * 4);    // 256 KB
  bf16*  woT     = (bf16*)alloc((size_t)512 * 512 * 2);     // 512 KB
  float* xw      = (float*)alloc((size_t)8192 * 256 * 4);   // 8 MB [q_lat|k_lat]
  bf16*  vt      = (bf16*)alloc((size_t)512 * 8192 * 2);    // 8 MB V^T
  bf16*  attn_bf = (bf16*)xw;                               // alias, 8 MB

  // Wcomb (cols 0..127 of wcat) = Wq @ Wuk^T
  gemm<true, false, false, false><<<dim3(2, 8), 256, 0, stream>>>(
      Wq, 512, Wuk, 512, wcat, 256, nullptr, 512);
  // Wckv -> cols 128..255 of wcat
  k_copy_wckv<<<256, 256, 0, stream>>>(Wckv, wcat);
  k_biascomb<<<256, 64, 0, stream>>>(bq, Wuk, bias_c);
  k_tr_f32<<<dim3(16, 4), 256, 0, stream>>>(Wuv, wuvT_f, 128, 512);
  k_tr_f32_bf16<<<dim3(16, 16), 256, 0, stream>>>(Wo, woT, 512, 512);
  // xw = x @ wcat + [bias_c | 0]
  gemm<false, true, false, false><<<dim3(4, 128), 256, 0, stream>>>(
      x, 512, wcat, 256, xw, 256, bias_c, 512);
  // vt(512x8192) = Wuv^T @ k_lat^T  (BT consumes k_lat rows of xw)
  gemm<true, false, false, true><<<dim3(128, 8), 256, 0, stream>>>(
      wuvT_f, 128, xw + 128, 256, vt, 8192, nullptr, 128);
  // qk_values + attn_weights
  k_qk3<<<dim3(128, 64), 256, 0, stream>>>(xw, mask, qk_out, aw_out);
  // attn = aw @ V  (MFMA; writes over xw — dead)
  k_pv_mfma<<<dim3(8, 64), 256, 0, stream>>>(aw_out, vt, attn_bf);
  // out = attn @ Wo + bo  (MFMA)
  gemm_mfma_out<<<dim3(4, 64), 256, 0, stream>>>(attn_bf, woT, out, bo);
  (void)in_sizes; (void)n_in; (void)out_size; (void)ws_size;
}